// Round 5
// baseline (1551.319 us; speedup 1.0000x reference)
//
#include <hip/hip_runtime.h>
#include <math.h>

#define Bb 16
#define Nn 2048
#define Dd 256
#define Cc 128
#define Kk 20
#define BIG_NEG -1.0e9f
#define LOG2E 1.4426950408889634f
#define LN2   0.6931471805599453f

// workspace layout (float offsets)
#define WS_EMIS   0
#define WS_MSC    (WS_EMIS + Bb*Nn*Cc)          // means * inv_var, bf16  [C][D]
#define WS_XQ     (WS_MSC + Cc*Dd)              // sum f^2*inv_var  [B*N]
#define WS_ECHAN  (WS_XQ + Bb*Nn)               // const - 0.5*mq   [C]
#define WS_T      (WS_ECHAN + Cc)               // exp(trans_lp)    [C][C]
#define WS_LEN    (WS_T + Cc*Cc)                // len_lp * LOG2E   [K][C]
#define WS_INIT   (WS_LEN + Kk*Cc)              // init_lp * LOG2E  [C]
#define WS_IVAR   (WS_INIT + Cc)                // 1/cov            [D]

typedef __attribute__((ext_vector_type(8))) short short8;
typedef __attribute__((ext_vector_type(4))) float float4v;
typedef __attribute__((ext_vector_type(8))) int int8v;

__device__ __forceinline__ unsigned short f32_to_bf16(float x) {
  unsigned int u = __builtin_bit_cast(unsigned int, x);
  u = (u + 0x7FFFu + ((u >> 16) & 1u)) >> 16;
  return (unsigned short)u;
}

#define DPP_STEP(x, op, ctrl, rmask)                                          \
  do {                                                                        \
    int _yi = __builtin_amdgcn_update_dpp(                                    \
        __builtin_bit_cast(int, x), __builtin_bit_cast(int, x), ctrl, rmask,  \
        0xF, true);                                                           \
    x = op(x, __builtin_bit_cast(float, _yi));                                \
  } while (0)

__device__ __forceinline__ float dpp_add(float a, float b) { return a + b; }

__device__ __forceinline__ float wave_max64(float x) {
  DPP_STEP(x, fmaxf, 0xB1, 0xF);
  DPP_STEP(x, fmaxf, 0x4E, 0xF);
  DPP_STEP(x, fmaxf, 0x141, 0xF);
  DPP_STEP(x, fmaxf, 0x140, 0xF);
  DPP_STEP(x, fmaxf, 0x142, 0xA);
  DPP_STEP(x, fmaxf, 0x143, 0xC);
  return __builtin_bit_cast(float,
      __builtin_amdgcn_readlane(__builtin_bit_cast(int, x), 63));
}

__device__ __forceinline__ float wave_sum64(float x) {
  DPP_STEP(x, dpp_add, 0xB1, 0xF);
  DPP_STEP(x, dpp_add, 0x4E, 0xF);
  DPP_STEP(x, dpp_add, 0x141, 0xF);
  DPP_STEP(x, dpp_add, 0x140, 0xF);
  DPP_STEP(x, dpp_add, 0x142, 0xA);
  DPP_STEP(x, dpp_add, 0x143, 0xC);
  return __builtin_bit_cast(float,
      __builtin_amdgcn_readlane(__builtin_bit_cast(int, x), 63));
}

// interleaved k-permutation: k-pos 2j <-> channel j, 2j+1 <-> channel 64+j
__device__ __forceinline__ int chan_of_k(int kpos) {
  return (kpos & 1) ? (64 + (kpos >> 1)) : (kpos >> 1);
}

// ---------------- small precompute (1 block, 256 threads) ----------------
__global__ void prep_kernel(const float* __restrict__ means,
                            const float* __restrict__ cov,
                            const float* __restrict__ tl,
                            const float* __restrict__ il,
                            const float* __restrict__ plr,
                            float* __restrict__ ws) {
  __shared__ float s_iv[Dd];
  __shared__ float s_red[4];
  __shared__ float s_tlse[Cc];
  int tid = threadIdx.x;

  float cv = cov[tid];
  float iv = 1.0f / cv;
  s_iv[tid] = iv;
  ws[WS_IVAR + tid] = iv;
  float lg = __logf(cv);
  #pragma unroll
  for (int off = 1; off < 64; off <<= 1) lg += __shfl_xor(lg, off, 64);
  if ((tid & 63) == 0) s_red[tid >> 6] = lg;
  __syncthreads();
  float logdet = s_red[0] + s_red[1] + s_red[2] + s_red[3];
  float cconst = -0.5f * ((float)Dd * 1.8378770664093453f + logdet);

  // msc in bf16 (B-frag operand for emission MFMA)
  unsigned short* mscb = (unsigned short*)(ws + WS_MSC);
  for (int idx = tid; idx < Cc * Dd; idx += 256) {
    int d = idx & (Dd - 1);
    mscb[idx] = f32_to_bf16(means[idx] * s_iv[d]);
  }
  if (tid < Cc) {
    float acc = 0.0f;
    for (int d = 0; d < Dd; d++) {
      float m = means[tid * Dd + d];
      acc = fmaf(m * m, s_iv[d], acc);
    }
    ws[WS_ECHAN + tid] = cconst - 0.5f * acc;
  }
  // Poisson length table in log2 units
  for (int idx = tid; idx < Kk * Cc; idx += 256) {
    int L = idx / Cc + 1;
    int c = idx & (Cc - 1);
    float r = plr[c];
    ws[WS_LEN + idx] = ((float)L * r - __expf(r) - lgammaf((float)(L + 1))) * LOG2E;
  }

  __syncthreads();
  float x = (tid < Cc) ? il[tid] : -INFINITY;
  float mx = x;
  #pragma unroll
  for (int off = 1; off < 64; off <<= 1) mx = fmaxf(mx, __shfl_xor(mx, off, 64));
  if ((tid & 63) == 0) s_red[tid >> 6] = mx;
  __syncthreads();
  float M = fmaxf(s_red[0], s_red[1]);
  float se = (tid < Cc) ? __expf(x - M) : 0.0f;
  #pragma unroll
  for (int off = 1; off < 64; off <<= 1) se += __shfl_xor(se, off, 64);
  __syncthreads();
  if ((tid & 63) == 0) s_red[tid >> 6] = se;
  __syncthreads();
  float lse = M + __logf(s_red[0] + s_red[1]);
  if (tid < Cc) ws[WS_INIT + tid] = (x - lse) * LOG2E;   // log2 units

  if (tid < Cc) {
    int j = tid;
    float m2 = -INFINITY;
    for (int i = 0; i < Cc; i++) if (i != j) m2 = fmaxf(m2, tl[i * Cc + j]);
    float s2 = 0.0f;
    for (int i = 0; i < Cc; i++) if (i != j) s2 += __expf(tl[i * Cc + j] - m2);
    s_tlse[j] = m2 + __logf(s2);
  }
  __syncthreads();
  for (int idx = tid; idx < Cc * Cc; idx += 256) {
    int i = idx / Cc;
    int j = idx & (Cc - 1);
    ws[WS_T + idx] = (i == j) ? 0.0f : __expf(tl[idx] - s_tlse[j]);
  }
}

// ---------------- xq[b,n] = sum_d f^2 * inv_var (one wave per position) ----------------
__global__ void xq_kernel(const float* __restrict__ f, float* __restrict__ ws) {
  int pos = blockIdx.x * 4 + (threadIdx.x >> 6);
  int lane = threadIdx.x & 63;
  const float4 fv = *(const float4*)&f[(size_t)pos * Dd + lane * 4];
  const float4 vv = *(const float4*)&ws[WS_IVAR + lane * 4];
  float a = fv.x * fv.x * vv.x + fv.y * fv.y * vv.y +
            fv.z * fv.z * vv.z + fv.w * fv.w * vv.w;
  #pragma unroll
  for (int off = 1; off < 64; off <<= 1) a += __shfl_xor(a, off, 64);
  if (lane == 0) ws[WS_XQ + pos] = a;
}

// ---------------- emission via MFMA: 32n x 128c per block, 4 waves; log2 units ----------------
__launch_bounds__(256)
__global__ void emis_mfma_kernel(const float* __restrict__ f, float* __restrict__ ws) {
  const unsigned short* msc = (const unsigned short*)(ws + WS_MSC);
  float* emis = ws + WS_EMIS;
  int tid = threadIdx.x;
  int w = tid >> 6, lane = tid & 63, g = lane >> 4, l16 = lane & 15;
  int b = blockIdx.x >> 6;
  int n0 = (blockIdx.x & 63) << 5;
  int c0 = w << 5;

  const float* fbase = f + (size_t)(b * Nn + n0) * Dd;
  float4v acc[2][2];
  #pragma unroll
  for (int rt = 0; rt < 2; rt++)
    #pragma unroll
    for (int ct = 0; ct < 2; ct++) acc[rt][ct] = (float4v){0.f, 0.f, 0.f, 0.f};

  #pragma unroll
  for (int k0 = 0; k0 < Dd; k0 += 32) {
    int kk = k0 + g * 8;
    short8 afr[2], bfr[2];
    #pragma unroll
    for (int rt = 0; rt < 2; rt++) {
      const float* src = fbase + (size_t)(rt * 16 + l16) * Dd + kk;
      float4 v0 = *(const float4*)src;
      float4 v1 = *(const float4*)(src + 4);
      short8 fr;
      fr[0] = (short)f32_to_bf16(v0.x); fr[1] = (short)f32_to_bf16(v0.y);
      fr[2] = (short)f32_to_bf16(v0.z); fr[3] = (short)f32_to_bf16(v0.w);
      fr[4] = (short)f32_to_bf16(v1.x); fr[5] = (short)f32_to_bf16(v1.y);
      fr[6] = (short)f32_to_bf16(v1.z); fr[7] = (short)f32_to_bf16(v1.w);
      afr[rt] = fr;
    }
    #pragma unroll
    for (int ct = 0; ct < 2; ct++)
      bfr[ct] = *(const short8*)&msc[(size_t)(c0 + ct * 16 + l16) * Dd + kk];
    #pragma unroll
    for (int rt = 0; rt < 2; rt++)
      #pragma unroll
      for (int ct = 0; ct < 2; ct++)
        acc[rt][ct] = __builtin_amdgcn_mfma_f32_16x16x32_bf16(afr[rt], bfr[ct], acc[rt][ct], 0, 0, 0);
  }

  #pragma unroll
  for (int rt = 0; rt < 2; rt++) {
    #pragma unroll
    for (int ct = 0; ct < 2; ct++) {
      int cc = c0 + ct * 16 + l16;
      float ec = ws[WS_ECHAN + cc];
      #pragma unroll
      for (int r = 0; r < 4; r++) {
        int row = rt * 16 + g * 4 + r;
        int nn = n0 + row;
        emis[(size_t)(b * Nn + nn) * Cc + cc] =
            (ec - 0.5f * ws[WS_XQ + b * Nn + nn] + acc[rt][ct][r]) * LOG2E;
      }
    }
  }
}

// ---------------- sequential semi-Markov scan: ONE WAVE per batch, no barriers ----------------
__launch_bounds__(64, 1)
__global__ void scan_kernel(const int* __restrict__ lengths,
                            const float* __restrict__ ws,
                            float* __restrict__ out) {
  __shared__ unsigned short s_p[64];   // 128 fp8 p-values, pair-interleaved
  int lane = threadIdx.x;              // 0..63
  int lg4 = lane >> 4, n16 = lane & 15;
  int b = blockIdx.x;
  int len_b = lengths[b];
  const float* emis = ws + WS_EMIS + (size_t)b * Nn * Cc;
  const int sc1 = 0x7F7F7F7F;          // E8M0 scale = 1.0 in all bytes

  // ---- T as fp8 B-frags for mfma_scale 16x16x128 (x64 into e4m3 range) ----
  // B[k][n]: n = nt*16 + (lane&15), k = (lane>>4)*32 + j ; channel = chan_of_k(k)
  int8v Tf[8];
  {
    const float* T = ws + WS_T;
    #pragma unroll
    for (int nt = 0; nt < 8; nt++) {
      const float* Trow = &T[(size_t)(nt * 16 + n16) * Cc];
      #pragma unroll
      for (int dw = 0; dw < 8; dw++) {
        int kbase = lg4 * 32 + dw * 4;
        float t0 = 64.0f * Trow[chan_of_k(kbase + 0)];
        float t1 = 64.0f * Trow[chan_of_k(kbase + 1)];
        float t2 = 64.0f * Trow[chan_of_k(kbase + 2)];
        float t3 = 64.0f * Trow[chan_of_k(kbase + 3)];
        int d = __builtin_amdgcn_cvt_pk_fp8_f32(t0, t1, 0, false);
        d = __builtin_amdgcn_cvt_pk_fp8_f32(t2, t3, d, true);
        Tf[nt][dw] = d;
      }
    }
  }

  // ---- per-channel constants (c0 = lane, c1 = lane+64), log2 units ----
  int cidx[2] = {lane, lane + 64};
  float len0[2], E2[2][Kk - 1];
  #pragma unroll
  for (int ch = 0; ch < 2; ch++) {
    float lenv[Kk];
    #pragma unroll
    for (int k = 0; k < Kk; k++) lenv[k] = ws[WS_LEN + k * Cc + cidx[ch]];
    len0[ch] = lenv[0];
    #pragma unroll
    for (int k = 0; k < Kk - 1; k++)
      E2[ch][k] = __builtin_amdgcn_exp2f(lenv[k + 1] - lenv[k]);
  }

  // ---- state: w[ch][j] = 2^(h[j+1] - a), sum-anchored; gnew in log2 ----
  float wv[2][Kk - 1];
  #pragma unroll
  for (int ch = 0; ch < 2; ch++)
    #pragma unroll
    for (int j = 0; j < Kk - 1; j++) wv[ch][j] = 0.0f;
  float a[2] = {0.0f, 0.0f};
  float L19[2] = {-1.0e30f, -1.0e30f};
  float gnew[2], cum[2];
  gnew[0] = ws[WS_INIT + lane];
  gnew[1] = ws[WS_INIT + lane + 64];
  cum[0] = emis[0 * Cc + lane];
  cum[1] = emis[0 * Cc + lane + 64];

  float e[2][8], en[2][8];
  #pragma unroll
  for (int i = 0; i < 8; i++) {
    e[0][i] = emis[(size_t)(1 + i) * Cc + lane];
    e[1][i] = emis[(size_t)(1 + i) * Cc + lane + 64];
  }

  bool done = false;
  for (int tg = 1; tg <= Nn && !done; tg += 8) {
    #pragma unroll
    for (int i = 0; i < 8; i++) {
      int t = tg + i;
      // prefetch (no barriers anywhere -> loads stay outstanding, no drains)
      {
        int r = tg + 8 + i; if (r > Nn - 1) r = Nn - 1;
        en[0][i] = emis[(size_t)r * Cc + lane];
        en[1][i] = emis[(size_t)r * Cc + lane + 64];
      }

      // ---- chain: per-channel LSE fixup (log-space anchor, jump-safe) ----
      float h0[2], mm[2], eh[2], sfix[2], mab[2];
      #pragma unroll
      for (int ch = 0; ch < 2; ch++) {
        h0[ch] = gnew[ch] + len0[ch];
        mm[ch] = fmaxf(L19[ch], h0[ch]);
        float eL = __builtin_amdgcn_exp2f(L19[ch] - mm[ch]);
        eh[ch] = __builtin_amdgcn_exp2f(h0[ch] - mm[ch]);
        sfix[ch] = eL + eh[ch];
        mab[ch] = mm[ch] + cum[ch];
      }
      float lmax = fmaxf(mab[0], mab[1]);
      float wm = wave_max64(lmax);
      float p0 = sfix[0] * __builtin_amdgcn_exp2f(mab[0] - wm);   // <= 2
      float p1 = sfix[1] * __builtin_amdgcn_exp2f(mab[1] - wm);
      int pk = __builtin_amdgcn_cvt_pk_fp8_f32(p0, p1, 0, false);
      s_p[lane] = (unsigned short)pk;
      bool is_out = (t == len_b);

      // ---- A-frag: 32 fp8 k-bytes (same-wave LDS, in-order, no barrier) ----
      const int4* ap = (const int4*)((const char*)s_p + lg4 * 32);
      int4 ra = ap[0];
      int4 rb = ap[1];
      int8v A;
      A[0] = ra.x; A[1] = ra.y; A[2] = ra.z; A[3] = ra.w;
      A[4] = rb.x; A[5] = rb.y; A[6] = rb.z; A[7] = rb.w;

      // ---- matvec: q*64 = T64 x p, one K=128 MFMA per 16 outputs ----
      float4v D0, D1, D2, D3, D4, D5, D6, D7;
      {
        float4v z = {0.0f, 0.0f, 0.0f, 0.0f};
        D0 = __builtin_amdgcn_mfma_scale_f32_16x16x128_f8f6f4(A, Tf[0], z, 0, 0, 0, sc1, 0, sc1);
        D1 = __builtin_amdgcn_mfma_scale_f32_16x16x128_f8f6f4(A, Tf[1], z, 0, 0, 0, sc1, 0, sc1);
        D2 = __builtin_amdgcn_mfma_scale_f32_16x16x128_f8f6f4(A, Tf[2], z, 0, 0, 0, sc1, 0, sc1);
        D3 = __builtin_amdgcn_mfma_scale_f32_16x16x128_f8f6f4(A, Tf[3], z, 0, 0, 0, sc1, 0, sc1);
        D4 = __builtin_amdgcn_mfma_scale_f32_16x16x128_f8f6f4(A, Tf[4], z, 0, 0, 0, sc1, 0, sc1);
        D5 = __builtin_amdgcn_mfma_scale_f32_16x16x128_f8f6f4(A, Tf[5], z, 0, 0, 0, sc1, 0, sc1);
        D6 = __builtin_amdgcn_mfma_scale_f32_16x16x128_f8f6f4(A, Tf[6], z, 0, 0, 0, sc1, 0, sc1);
        D7 = __builtin_amdgcn_mfma_scale_f32_16x16x128_f8f6f4(A, Tf[7], z, 0, 0, 0, sc1, 0, sc1);
      }

      // ---- shadow: shift window multiplicatively, re-anchor to mm ----
      float S19n[2];
      #pragma unroll
      for (int ch = 0; ch < 2; ch++) {
        float phi = __builtin_amdgcn_exp2f(a[ch] - mm[ch]);   // <= 1
        #pragma unroll
        for (int j = Kk - 2; j >= 1; j--)
          wv[ch][j] = wv[ch][j - 1] * (E2[ch][j] * phi);
        wv[ch][0] = eh[ch] * E2[ch][0];
        float s4[5];
        s4[0] = (wv[ch][0] + wv[ch][1]) + (wv[ch][2] + wv[ch][3]);
        s4[1] = (wv[ch][4] + wv[ch][5]) + (wv[ch][6] + wv[ch][7]);
        s4[2] = (wv[ch][8] + wv[ch][9]) + (wv[ch][10] + wv[ch][11]);
        s4[3] = (wv[ch][12] + wv[ch][13]) + (wv[ch][14] + wv[ch][15]);
        s4[4] = (wv[ch][16] + wv[ch][17]) + wv[ch][18];
        S19n[ch] = ((s4[0] + s4[1]) + (s4[2] + s4[3])) + s4[4];
      }

      // ---- extract q, close the recurrence ----
      float q0 = (lg4 == 0) ? D0[0] : (lg4 == 1) ? D1[0] : (lg4 == 2) ? D2[0] : D3[0];
      float q1 = (lg4 == 0) ? D4[0] : (lg4 == 1) ? D5[0] : (lg4 == 2) ? D6[0] : D7[0];
      float rel0 = cum[0] - wm;
      float rel1 = cum[1] - wm;
      gnew[0] = (q0 > 0.0f) ? (__builtin_amdgcn_logf(q0) - 6.0f - rel0) : BIG_NEG;
      gnew[1] = (q1 > 0.0f) ? (__builtin_amdgcn_logf(q1) - 6.0f - rel1) : BIG_NEG;

      if (is_out) {
        float psum = wave_sum64(p0 + p1);
        if (lane == 0) out[b] = LN2 * (wm + __builtin_amdgcn_logf(psum));
        done = true;
        break;
      }

      // ---- commit state ----
      #pragma unroll
      for (int ch = 0; ch < 2; ch++) {
        a[ch] = mm[ch];
        L19[ch] = mm[ch] + __builtin_amdgcn_logf(S19n[ch]);
        cum[ch] += e[ch][i];
      }
    }
    if (!done) {
      #pragma unroll
      for (int i = 0; i < 8; i++) { e[0][i] = en[0][i]; e[1][i] = en[1][i]; }
    }
  }
}

extern "C" void kernel_launch(void* const* d_in, const int* in_sizes, int n_in,
                              void* d_out, int out_size, void* d_ws, size_t ws_size,
                              hipStream_t stream) {
  const float* features = (const float*)d_in[0];
  const int* lengths = (const int*)d_in[1];
  const float* means = (const float*)d_in[2];
  const float* cov = (const float*)d_in[3];
  const float* tl = (const float*)d_in[4];
  const float* il = (const float*)d_in[5];
  const float* plr = (const float*)d_in[6];
  float* out = (float*)d_out;
  float* ws = (float*)d_ws;

  prep_kernel<<<1, 256, 0, stream>>>(means, cov, tl, il, plr, ws);
  xq_kernel<<<(Bb * Nn) / 4, 256, 0, stream>>>(features, ws);
  emis_mfma_kernel<<<Bb * (Nn / 32), 256, 0, stream>>>(features, ws);
  scan_kernel<<<Bb, 64, 0, stream>>>(lengths, ws, out);
}